// Round 18
// baseline (383.349 us; speedup 1.0000x reference)
//
#include <hip/hip_runtime.h>
#include <hip/hip_bf16.h>
#include <math.h>
#include <stdint.h>

// ---------------------------------------------------------------------------
// Attention (B=4, N=2048, D=512, H=8, Dh=64) for MI355X.
// Precision plan (threshold 6.48e-3; measured floor 1.95e-3):
//   x@Wqkv: 1-term bf16.  QK^T: bf16.  PV: bf16 P,V.  AO bf16; out GEMM
//   1-term.  Split-KV partials bf16, m/s f32 (exact log2-domain 4-way merge).
// R18: occupancy x2 -> KV tile 32 (LDS 32KB: KV dbuf 16K + 8x2K P) + 4-way
// split-KV (grid 1024 = 4 blocks/CU x 8 waves = 32 waves/CU, launch_bounds
// (512,8) pins VGPR<=64). 1 gld16/thread/tile, vmcnt(1). Separate 4-way
// combine kernel; k_gemm_out reverted to simple R15 form.
// ---------------------------------------------------------------------------

typedef unsigned short u16;
typedef __attribute__((ext_vector_type(4))) float f32x4;
typedef __attribute__((ext_vector_type(8))) short bf16x8;   // 8 bf16 = 4 VGPRs
typedef __attribute__((ext_vector_type(4))) short s16x4;

#define AS1 __attribute__((address_space(1)))
#define AS3 __attribute__((address_space(3)))
#define MFMA(a, b, c) __builtin_amdgcn_mfma_f32_16x16x32_bf16(a, b, c, 0, 0, 0)
#define QSCALE 0.180336880f   /* 0.125 * log2(e): logits in log2 domain */

// OP quarter element offsets (u16 units) in workspace
#define QOFF0 0
#define QOFF1 4194304
#define QOFF2 27262976
#define QOFF3 31457280

__device__ __forceinline__ u16 f2bf(float f) {
  union { float f; unsigned u; } v; v.f = f;
  unsigned r = v.u + 0x7FFFu + ((v.u >> 16) & 1u);   // RNE
  return (u16)(r >> 16);
}
__device__ __forceinline__ float bf2f(u16 b) {
  union { unsigned u; float f; } v; v.u = ((unsigned)b) << 16; return v.f;
}
__device__ __forceinline__ void gld16(const u16* g, u16* l) {
  __builtin_amdgcn_global_load_lds((const AS1 void*)g, (AS3 void*)l, 16, 0, 0);
}
__device__ __forceinline__ float u2f(unsigned u) {
  union { unsigned u; float f; } v; v.u = u; return v.f;
}
__device__ __forceinline__ unsigned f2u(float f) {
  union { float f; unsigned u; } v; v.f = f; return v.u;
}
__device__ __forceinline__ int cvtpk(float lo, float hi) {
  int r; asm("v_cvt_pk_bf16_f32 %0, %1, %2" : "=v"(r) : "v"(lo), "v"(hi));
  return r;
}
__device__ __forceinline__ float fexp2(float x) {
  float r; asm("v_exp_f32 %0, %1" : "=v"(r) : "v"(x));
  return r;
}

// ---------------- merged prep (R17) ----------------------------------------
__global__ __launch_bounds__(256) void k_prep(
    const float* __restrict__ x,    u16* __restrict__ xh,
    const float* __restrict__ wqkv, u16* __restrict__ wqh,
    const float* __restrict__ wout, u16* __restrict__ woh) {
  const int bid = blockIdx.x, tid = threadIdx.x;
  if (bid < 4096) {
    int i = (bid * 256 + tid) * 4;
    f32x4 v = *(const f32x4*)&x[i];
    s16x4 hh;
    #pragma unroll
    for (int j = 0; j < 4; ++j) hh[j] = (short)f2bf(v[j]);
    *(s16x4*)&xh[i] = hh;
    return;
  }
  __shared__ u16 lds[64][66];
  const float* src; u16* dst; int N, n0, k0;
  if (bid < 4288) {
    const int b2 = bid - 4096;
    src = wqkv; dst = wqh; N = 1536;
    n0 = (b2 % 24) * 64; k0 = (b2 / 24) * 64;
  } else {
    const int b3 = bid - 4288;
    src = wout; dst = woh; N = 512;
    n0 = (b3 & 7) * 64; k0 = (b3 >> 3) * 64;
  }
  const int c = tid & 63, q = tid >> 6;
  #pragma unroll
  for (int s = 0; s < 16; ++s) {
    const int kr = q * 16 + s;
    lds[c][kr] = f2bf(src[(size_t)(k0 + kr) * N + n0 + c]);
  }
  __syncthreads();
  #pragma unroll
  for (int s = 0; s < 16; ++s) {
    const int nr = q * 16 + s;
    dst[(size_t)(n0 + nr) * 512 + k0 + c] = lds[nr][c];
  }
}

// ---------------- GEMM core: C[128x128], K=512, BK=32, 1-term, dbuf --------
__device__ __forceinline__ void gemm_core(
    const u16* __restrict__ Ah, const u16* __restrict__ Bh,
    char* sm, int rowA, int rowB, int tid, f32x4 (&acc)[4][4]) {
  const int wid = tid >> 6, lane = tid & 63;
  const int x = lane & 15, h = lane >> 4;
  const int wr = wid >> 1, wc = wid & 1;
  const int d0 = tid * 16;
  const int lg0 = d0 ^ (((d0 >> 7) & 7) << 4);
  const int srow = lg0 >> 6;
  const int scol = (lg0 & 63) >> 1;
  const int swk = ((lane >> 1) & 7) << 4;
  const int rdoA = ((wr * 64 + x) * 64 + h * 16) ^ swk;
  const int rdoB = (((wc * 64 + x) * 64 + h * 16) ^ swk) + 8192;

  {
    #pragma unroll
    for (int r = 0; r < 2; ++r) {
      const size_t ga = (size_t)(rowA + r * 64 + srow) * 512 + scol;
      const size_t gb = (size_t)(rowB + r * 64 + srow) * 512 + scol;
      gld16(Ah + ga, (u16*)(sm + r * 4096 + d0));
      gld16(Bh + gb, (u16*)(sm + 8192 + r * 4096 + d0));
    }
  }

  for (int kt = 0; kt < 16; ++kt) {
    const int bb = (kt & 1) * 16384;
    __builtin_amdgcn_s_barrier();
    if (kt < 15) {
      const int kofs = (kt + 1) * 32;
      char* buf = sm + (16384 - bb);
      #pragma unroll
      for (int r = 0; r < 2; ++r) {
        const size_t ga = (size_t)(rowA + r * 64 + srow) * 512 + kofs + scol;
        const size_t gb = (size_t)(rowB + r * 64 + srow) * 512 + kofs + scol;
        gld16(Ah + ga, (u16*)(buf + r * 4096 + d0));
        gld16(Bh + gb, (u16*)(buf + 8192 + r * 4096 + d0));
      }
      asm volatile("s_waitcnt vmcnt(4)" ::: "memory");
    } else {
      asm volatile("s_waitcnt vmcnt(0)" ::: "memory");
    }
    __builtin_amdgcn_s_barrier();

    bf16x8 a_h[4], b_h[4];
    #pragma unroll
    for (int i = 0; i < 4; ++i)
      a_h[i] = *(const bf16x8*)(sm + bb + rdoA + i * 1024);
    #pragma unroll
    for (int j = 0; j < 4; ++j)
      b_h[j] = *(const bf16x8*)(sm + bb + rdoB + j * 1024);
    __builtin_amdgcn_s_setprio(1);
    #pragma unroll
    for (int i = 0; i < 4; ++i)
      #pragma unroll
      for (int j = 0; j < 4; ++j)
        acc[i][j] = MFMA(a_h[i], b_h[j], acc[i][j]);
    __builtin_amdgcn_s_setprio(0);
  }
}

// ---------------- QKV projection (1-term) ----------------------------------
__global__ __launch_bounds__(256) void k_gemm_qkv(
    const u16* __restrict__ Ah, const u16* __restrict__ Bh,
    u16* __restrict__ Qb, u16* __restrict__ Kb, u16* __restrict__ Vt) {
  __shared__ __align__(1024) char sm[32768];
  const int tid = threadIdx.x, lane = tid & 63, wid = tid >> 6;
  const int x = lane & 15, h = lane >> 4;
  const int wr = wid >> 1, wc = wid & 1;
  const int rowA = blockIdx.x * 128, rowB = blockIdx.y * 128;
  f32x4 acc[4][4] = {};
  gemm_core(Ah, Bh, sm, rowA, rowB, tid, acc);

  #pragma unroll
  for (int i = 0; i < 4; ++i)
    #pragma unroll
    for (int j = 0; j < 4; ++j) {
      const int n = rowB + wc * 64 + j * 16 + x;
      const int which = n >> 9;
      const int hh = (n >> 6) & 7, d = n & 63;
      const int m0 = rowA + wr * 64 + i * 16 + h * 4;
      const int b = m0 >> 11, is0 = m0 & 2047;
      if (which == 0) {
        #pragma unroll
        for (int r = 0; r < 4; ++r) {
          const size_t idx = ((size_t)((b * 8 + hh) * 2048 + is0 + r)) * 64 + d;
          Qb[idx] = f2bf(acc[i][j][r] * QSCALE);
        }
      } else if (which == 1) {
        #pragma unroll
        for (int r = 0; r < 4; ++r) {
          const size_t idx = ((size_t)((b * 8 + hh) * 2048 + is0 + r)) * 64 + d;
          Kb[idx] = f2bf(acc[i][j][r]);
        }
      } else {
        s16x4 vv;
        #pragma unroll
        for (int r = 0; r < 4; ++r) vv[r] = (short)f2bf(acc[i][j][r]);
        *(s16x4*)&Vt[((size_t)((b * 8 + hh) * 64 + d)) * 2048 + is0] = vv;
      }
    }
}

// ---------------- output projection (1-term, simple A=AO) ------------------
__global__ __launch_bounds__(256) void k_gemm_out(
    const u16* __restrict__ Ah, const u16* __restrict__ Bh,
    const float* __restrict__ bias, float* __restrict__ out) {
  __shared__ __align__(1024) char sm[32768];
  const int tid = threadIdx.x, lane = tid & 63, wid = tid >> 6;
  const int x = lane & 15, h = lane >> 4;
  const int wr = wid >> 1, wc = wid & 1;
  const int rowA = blockIdx.x * 128, rowB = blockIdx.y * 128;
  f32x4 acc[4][4] = {};
  gemm_core(Ah, Bh, sm, rowA, rowB, tid, acc);

  #pragma unroll
  for (int i = 0; i < 4; ++i)
    #pragma unroll
    for (int j = 0; j < 4; ++j) {
      const int n = rowB + wc * 64 + j * 16 + x;
      #pragma unroll
      for (int r = 0; r < 4; ++r) {
        const int m = rowA + wr * 64 + i * 16 + h * 4 + r;
        out[(size_t)m * 512 + n] = acc[i][j][r] + bias[n];
      }
    }
}

// ---------------- flash attention, split-KV quarter, KV tile 32 -------------
// Grid 1024 (8qb x 32bh x 4 quarters, XCD-swizzled), 512 thr = 8 waves x 32q.
// Each block: 16 KV tiles of 32.  LDS 32KB: dbuf 2x8KB {K 2x2KB chunks, V
// 4KB} + 8x per-wave P 2KB.  1 gld16/thread/tile (waves 0-3 K, 4-7 V),
// counted vmcnt(1).  4 blocks/CU x 8 waves = 32 waves/CU.
__global__ __launch_bounds__(512, 8) void k_attn(
    const u16* __restrict__ Qb,
    const u16* __restrict__ Kb, const u16* __restrict__ Vt,
    u16* __restrict__ OP,          // quarters at QOFF0..3 (u16 units)
    float* __restrict__ Mm,        // [4][65536]
    float* __restrict__ Sm) {      // [4][65536]
  __shared__ __align__(1024) char sm[32768];
  const int tid = threadIdx.x, wid = tid >> 6, lane = tid & 63;
  const int x = lane & 15, h = lane >> 4;

  // XCD swizzle (1024 % 8 == 0): 4 bh per XCD; quarters co-located
  const int fid = blockIdx.x;
  const int l = (fid & 7) * 128 + (fid >> 3);
  const int quarter = l & 3, qb = (l >> 2) & 7, bh = l >> 5;

  const size_t base = (size_t)bh * 2048 * 64;   // Q/K [bh][2048][64]; Vt [bh][64][2048]
  const int qr0 = qb * 256 + wid * 32;
  const size_t kv0 = (size_t)quarter * 512;      // first kv of this quarter

  // Q B-frags per group g: lane (x,h) holds Q[qr0+g*16+x][d=ks*32+h*8+j]
  bf16x8 qh[2][2];
  #pragma unroll
  for (int g = 0; g < 2; ++g) {
    const size_t rq = base + (size_t)(qr0 + g * 16 + x) * 64 + h * 8;
    #pragma unroll
    for (int ks = 0; ks < 2; ++ks)
      qh[g][ks] = *(const bf16x8*)&Qb[rq + ks * 32];
  }

  bf16x8 ones;
  #pragma unroll
  for (int j = 0; j < 8; ++j) ones[j] = (short)0x3F80;   // bf16 1.0

  // staging: db=tid*16; [0,4K)=K (2x2KB chunks [32kv][32d]), [4K,8K)=V
  // ([64d][32kv]); source pre-swizzled by the involution.
  const int db = tid * 16;
  const u16* srcBase;
  size_t stOff, stMul;
  if (db < 4096) {
    const int ks = (db >> 11) & 1, bc = db & 2047;
    const int lg = bc ^ (((bc >> 7) & 7) << 4);
    stOff = (size_t)(lg >> 6) * 64 + ks * 32 + ((lg & 63) >> 1);
    stMul = 64;                    // addr = Kb + base + kvb*64 + stOff
    srcBase = Kb + base;
  } else {
    const int bv = db - 4096;
    const int lg = bv ^ (((bv >> 7) & 7) << 4);
    stOff = (size_t)(lg >> 6) * 2048 + ((lg & 63) >> 1);
    stMul = 1;                     // addr = Vt + base + kvb + stOff
    srcBase = Vt + base;
  }

  const int swk = ((lane >> 1) & 7) << 4;   // read xor for 64B-row tiles
  const int rdo = (x * 64 + h * 16) ^ swk;  // K/V per-lane read base
  char* const pb = sm + 16384 + wid * 2048; // per-wave P [2 g][16 q][32 kv]
  const int pxor = (x & 7) << 4;
  const int pwr = (x * 64) ^ pxor;          // involution on (q*64 + k*2)

  float mrun[2] = {-INFINITY, -INFINITY};
  f32x4 o[2][4] = {};
  f32x4 os[2] = {};

  // stage tile 0 -> buf0 (1 load/thread)
  gld16(srcBase + kv0 * stMul + stOff, (u16*)(sm + db));

  for (int kv = 0; kv < 16; ++kv) {
    const int bb = (kv & 1) * 8192;
    __builtin_amdgcn_s_barrier();
    if (kv < 15) {
      const size_t kvb = kv0 + (size_t)(kv + 1) * 32;
      gld16(srcBase + kvb * stMul + stOff, (u16*)(sm + (8192 - bb) + db));
      asm volatile("s_waitcnt vmcnt(1)" ::: "memory");  // prev tile landed
    } else {
      asm volatile("s_waitcnt vmcnt(0)" ::: "memory");
    }
    __builtin_amdgcn_s_barrier();

    const char* smb = sm + bb + rdo;

    // ---- S^T = K Q^T (bf16; Q pre-scaled by 0.125*log2e)
    f32x4 s[2][2] = {};
    __builtin_amdgcn_s_setprio(1);
    #pragma unroll
    for (int c = 0; c < 2; ++c)
      #pragma unroll
      for (int ks = 0; ks < 2; ++ks) {
        bf16x8 kb_ = *(const bf16x8*)(smb + ks * 2048 + c * 1024);
        s[0][c] = MFMA(kb_, qh[0][ks], s[0][c]);
        s[1][c] = MFMA(kb_, qh[1][ks], s[1][c]);
      }
    __builtin_amdgcn_s_setprio(0);

    // ---- per-group row max (8 local) + 2-shfl cross reduce
    float pm[2];
    #pragma unroll
    for (int g = 0; g < 2; ++g) {
      float m0 = fmaxf(fmaxf(s[g][0][0], s[g][0][1]),
                       fmaxf(s[g][0][2], s[g][0][3]));
      float m1 = fmaxf(fmaxf(s[g][1][0], s[g][1][1]),
                       fmaxf(s[g][1][2], s[g][1][3]));
      float p = fmaxf(m0, m1);
      p = fmaxf(p, __shfl_xor(p, 16, 64));
      p = fmaxf(p, __shfl_xor(p, 32, 64));
      pm[g] = p;
    }

    // ---- defer-rescale (THR=7 in log2; P bounded by 128)
    if (__any((pm[0] > mrun[0] + 7.0f) || (pm[1] > mrun[1] + 7.0f))) {
      #pragma unroll
      for (int g = 0; g < 2; ++g) {
        float mnew = fmaxf(mrun[g], pm[g]);
        float scl = fexp2(mrun[g] - mnew);
        mrun[g] = mnew;
        #pragma unroll
        for (int r = 0; r < 4; ++r) {
          float sq = u2f((unsigned)__builtin_amdgcn_ds_bpermute(
              (20 * h + r) * 4, (int)f2u(scl)));
          os[g][r] *= sq;
          #pragma unroll
          for (int dg = 0; dg < 4; ++dg) o[g][dg][r] *= sq;
        }
      }
    }

    // ---- P = exp2(S - mrun) -> bf16 pairs -> per-wave LDS [2g][16q][32kv]
    #pragma unroll
    for (int g = 0; g < 2; ++g)
      #pragma unroll
      for (int c = 0; c < 2; ++c) {
        int w0 = cvtpk(fexp2(s[g][c][0] - mrun[g]),
                       fexp2(s[g][c][1] - mrun[g]));
        int w1 = cvtpk(fexp2(s[g][c][2] - mrun[g]),
                       fexp2(s[g][c][3] - mrun[g]));
        int* dst = (int*)(pb + g * 1024 +
                          ((x * 64 + c * 32 + h * 8) ^ pxor));
        dst[0] = w0; dst[1] = w1;
      }

    // ---- PV + row-sum (same-wave P readback; no barrier)
    __builtin_amdgcn_s_setprio(1);
    {
      bf16x8 pa0 = *(const bf16x8*)(pb + ((x * 64 + h * 16) ^ pxor));
      bf16x8 pa1 = *(const bf16x8*)(pb + 1024 + ((x * 64 + h * 16) ^ pxor));
      os[0] = MFMA(pa0, ones, os[0]);
      os[1] = MFMA(pa1, ones, os[1]);
      #pragma unroll
      for (int dg = 0; dg < 4; ++dg) {
        bf16x8 vb = *(const bf16x8*)(smb + 4096 + dg * 1024);
        o[0][dg] = MFMA(pa0, vb, o[0][dg]);
        o[1][dg] = MFMA(pa1, vb, o[1][dg]);
      }
    }
    __builtin_amdgcn_s_setprio(0);
  }

  // ---- write partial O (bf16, unnormalized), m (h==0), s (x==0)
  const size_t qoff = (quarter == 0) ? QOFF0 : (quarter == 1) ? QOFF1
                    : (quarter == 2) ? QOFF2 : QOFF3;
  u16* op = OP + qoff + ((size_t)(bh * 2048 + qr0)) * 64;
  const int msbase = quarter * 65536 + bh * 2048 + qr0;
  #pragma unroll
  for (int g = 0; g < 2; ++g) {
    #pragma unroll
    for (int r = 0; r < 4; ++r) {
      const int row = g * 16 + h * 4 + r;
      #pragma unroll
      for (int dg = 0; dg < 4; ++dg)
        op[(size_t)row * 64 + dg * 16 + x] = f2bf(o[g][dg][r]);
      if (x == 0)
        Sm[msbase + g * 16 + h * 4 + r] = os[g][r];
    }
    if (h == 0)
      Mm[msbase + g * 16 + x] = mrun[g];
  }
}

// ---------------- combine: 4-way exact log2-domain merge --------------------
__global__ __launch_bounds__(256) void k_combine(
    const u16* __restrict__ OP, const float* __restrict__ Mm,
    const float* __restrict__ Sm, u16* __restrict__ AO) {
  const int gi = blockIdx.x * 256 + threadIdx.x;
  const int d4 = (gi & 15) * 4;
  const int rb = gi >> 4;                    // bh*2048 + row
  float m[4], s[4];
  #pragma unroll
  for (int i = 0; i < 4; ++i) {
    m[i] = Mm[i * 65536 + rb];
    s[i] = Sm[i * 65536 + rb];
  }
  const float mx = fmaxf(fmaxf(m[0], m[1]), fmaxf(m[2], m[3]));
  float a[4], den = 0.f;
  #pragma unroll
  for (int i = 0; i < 4; ++i) { a[i] = fexp2(m[i] - mx); den += s[i] * a[i]; }
  const float inv = 1.0f / den;

  const size_t qo[4] = {QOFF0, QOFF1, QOFF2, QOFF3};
  float acc4[4] = {0.f, 0.f, 0.f, 0.f};
  #pragma unroll
  for (int i = 0; i < 4; ++i) {
    const float w = a[i] * inv;
    s16x4 p = *(const s16x4*)&OP[qo[i] + (size_t)rb * 64 + d4];
    #pragma unroll
    for (int j = 0; j < 4; ++j) acc4[j] += bf2f((u16)p[j]) * w;
  }
  const int bh = rb >> 11, row = rb & 2047;
  const int b = bh >> 3, head = bh & 7;
  s16x4 r_;
  #pragma unroll
  for (int j = 0; j < 4; ++j) r_[j] = (short)f2bf(acc4[j]);
  *(s16x4*)&AO[((size_t)(b * 2048 + row)) * 512 + head * 64 + d4] = r_;
}

// ---------------------------------------------------------------------------
extern "C" void kernel_launch(void* const* d_in, const int* in_sizes, int n_in,
                              void* d_out, int out_size, void* d_ws, size_t ws_size,
                              hipStream_t stream) {
  const float* x    = (const float*)d_in[0];
  const float* wqkv = (const float*)d_in[1];
  const float* wout = (const float*)d_in[2];
  const float* bout = (const float*)d_in[3];
  float* out = (float*)d_out;

  char* w = (char*)d_ws;
  u16* xh  = (u16*)(w + 0);           // 8192x512 bf16 (dead after qkv)
  u16* wqh = (u16*)(w + 16777216);    // WqkvT [1536][512] (dead after qkv)
  u16* woh = (u16*)(w + 19922944);    // WoutT [512][512] (live to end)
  u16* Qb  = (u16*)(w + 20971520);    // [32][2048][64] bf16 (dead after attn)
  u16* Kb  = (u16*)(w + 37748736);    // [32][2048][64] bf16
  u16* Vt  = (u16*)(w + 46137344);    // [32][64][2048] bf16 (ends 54525952)
  // Split-KV partials: quarters q0@0, q1@8388608, q2@54525952, q3@62914560
  u16*   OP = (u16*)(w + 0);
  float* Mm = (float*)(w + 16777216); // [4][65536] f32 (aliases dead wqh tail ok)
  float* Sm = (float*)(w + 17825792); // [4][65536] f32 (ends 18874368 < woh)
  u16*   AO = (u16*)(w + 20971520);   // [8192][512] bf16 (aliases dead Qb)

  k_prep<<<4352, 256, 0, stream>>>(x, xh, wqkv, wqh, wout, woh);
  k_gemm_qkv<<<dim3(64, 12), 256, 0, stream>>>(xh, wqh, Qb, Kb, Vt);
  k_attn<<<1024, 512, 0, stream>>>(Qb, Kb, Vt, OP, Mm, Sm);
  k_combine<<<4096, 256, 0, stream>>>(OP, Mm, Sm, AO);
  k_gemm_out<<<dim3(64, 4), 256, 0, stream>>>(AO, woh, bout, out);
}

// Round 19
// 93.119 us; speedup vs baseline: 4.1168x; 4.1168x over previous
//
#include <hip/hip_runtime.h>
#include <hip/hip_bf16.h>
#include <math.h>
#include <stdint.h>

// ---------------------------------------------------------------------------
// Attention (B=4, N=2048, D=512, H=8, Dh=64) for MI355X.
// Precision plan (threshold 6.48e-3; measured floor 1.95e-3):
//   x@Wqkv: 1-term bf16.  QK^T: bf16.  PV: bf16 P,V.  out GEMM 1-term with
//   fused exact log2-domain split-KV merge on the A-operand.
// R19: revert to R17 (best: 93.2us). R18's forced launch_bounds(512,8)
// spilled all state (VGPR 32, FETCH 738MB, 334us) -- occupancy cannot be
// bought below the live-state VGPR footprint.
// ---------------------------------------------------------------------------

typedef unsigned short u16;
typedef __attribute__((ext_vector_type(4))) float f32x4;
typedef __attribute__((ext_vector_type(8))) short bf16x8;   // 8 bf16 = 4 VGPRs
typedef __attribute__((ext_vector_type(4))) short s16x4;

#define AS1 __attribute__((address_space(1)))
#define AS3 __attribute__((address_space(3)))
#define MFMA(a, b, c) __builtin_amdgcn_mfma_f32_16x16x32_bf16(a, b, c, 0, 0, 0)
#define QSCALE 0.180336880f   /* 0.125 * log2(e): logits in log2 domain */

__device__ __forceinline__ u16 f2bf(float f) {
  union { float f; unsigned u; } v; v.f = f;
  unsigned r = v.u + 0x7FFFu + ((v.u >> 16) & 1u);   // RNE
  return (u16)(r >> 16);
}
__device__ __forceinline__ float bf2f(u16 b) {
  union { unsigned u; float f; } v; v.u = ((unsigned)b) << 16; return v.f;
}
__device__ __forceinline__ void gld16(const u16* g, u16* l) {
  __builtin_amdgcn_global_load_lds((const AS1 void*)g, (AS3 void*)l, 16, 0, 0);
}
__device__ __forceinline__ float u2f(unsigned u) {
  union { unsigned u; float f; } v; v.u = u; return v.f;
}
__device__ __forceinline__ unsigned f2u(float f) {
  union { float f; unsigned u; } v; v.f = f; return v.u;
}
__device__ __forceinline__ int cvtpk(float lo, float hi) {
  int r; asm("v_cvt_pk_bf16_f32 %0, %1, %2" : "=v"(r) : "v"(lo), "v"(hi));
  return r;
}
__device__ __forceinline__ float fexp2(float x) {
  float r; asm("v_exp_f32 %0, %1" : "=v"(r) : "v"(x));
  return r;
}

// ---------------- merged prep --------------------------------------------
__global__ __launch_bounds__(256) void k_prep(
    const float* __restrict__ x,    u16* __restrict__ xh,
    const float* __restrict__ wqkv, u16* __restrict__ wqh,
    const float* __restrict__ wout, u16* __restrict__ woh) {
  const int bid = blockIdx.x, tid = threadIdx.x;
  if (bid < 4096) {                       // x: 4M f32 -> bf16, vec4
    int i = (bid * 256 + tid) * 4;
    f32x4 v = *(const f32x4*)&x[i];
    s16x4 hh;
    #pragma unroll
    for (int j = 0; j < 4; ++j) hh[j] = (short)f2bf(v[j]);
    *(s16x4*)&xh[i] = hh;
    return;
  }
  __shared__ u16 lds[64][66];
  const float* src; u16* dst; int N, n0, k0;
  if (bid < 4288) {
    const int b2 = bid - 4096;
    src = wqkv; dst = wqh; N = 1536;
    n0 = (b2 % 24) * 64; k0 = (b2 / 24) * 64;
  } else {
    const int b3 = bid - 4288;
    src = wout; dst = woh; N = 512;
    n0 = (b3 & 7) * 64; k0 = (b3 >> 3) * 64;
  }
  const int c = tid & 63, q = tid >> 6;
  #pragma unroll
  for (int s = 0; s < 16; ++s) {          // coalesced f32 row reads
    const int kr = q * 16 + s;
    lds[c][kr] = f2bf(src[(size_t)(k0 + kr) * N + n0 + c]);
  }
  __syncthreads();
  #pragma unroll
  for (int s = 0; s < 16; ++s) {          // coalesced bf16 row writes
    const int nr = q * 16 + s;
    dst[(size_t)(n0 + nr) * 512 + k0 + c] = lds[nr][c];
  }
}

// ---------------- GEMM core: C[128x128], K=512, BK=32, 1-term, dbuf --------
__device__ __forceinline__ void gemm_core(
    const u16* __restrict__ Ah, const u16* __restrict__ Bh,
    char* sm, int rowA, int rowB, int tid, f32x4 (&acc)[4][4]) {
  const int wid = tid >> 6, lane = tid & 63;
  const int x = lane & 15, h = lane >> 4;
  const int wr = wid >> 1, wc = wid & 1;
  const int d0 = tid * 16;
  const int lg0 = d0 ^ (((d0 >> 7) & 7) << 4);
  const int srow = lg0 >> 6;
  const int scol = (lg0 & 63) >> 1;
  const int swk = ((lane >> 1) & 7) << 4;
  const int rdoA = ((wr * 64 + x) * 64 + h * 16) ^ swk;
  const int rdoB = (((wc * 64 + x) * 64 + h * 16) ^ swk) + 8192;

  {
    #pragma unroll
    for (int r = 0; r < 2; ++r) {
      const size_t ga = (size_t)(rowA + r * 64 + srow) * 512 + scol;
      const size_t gb = (size_t)(rowB + r * 64 + srow) * 512 + scol;
      gld16(Ah + ga, (u16*)(sm + r * 4096 + d0));
      gld16(Bh + gb, (u16*)(sm + 8192 + r * 4096 + d0));
    }
  }

  for (int kt = 0; kt < 16; ++kt) {
    const int bb = (kt & 1) * 16384;
    __builtin_amdgcn_s_barrier();
    if (kt < 15) {
      const int kofs = (kt + 1) * 32;
      char* buf = sm + (16384 - bb);
      #pragma unroll
      for (int r = 0; r < 2; ++r) {
        const size_t ga = (size_t)(rowA + r * 64 + srow) * 512 + kofs + scol;
        const size_t gb = (size_t)(rowB + r * 64 + srow) * 512 + kofs + scol;
        gld16(Ah + ga, (u16*)(buf + r * 4096 + d0));
        gld16(Bh + gb, (u16*)(buf + 8192 + r * 4096 + d0));
      }
      asm volatile("s_waitcnt vmcnt(4)" ::: "memory");
    } else {
      asm volatile("s_waitcnt vmcnt(0)" ::: "memory");
    }
    __builtin_amdgcn_s_barrier();

    bf16x8 a_h[4], b_h[4];
    #pragma unroll
    for (int i = 0; i < 4; ++i)
      a_h[i] = *(const bf16x8*)(sm + bb + rdoA + i * 1024);
    #pragma unroll
    for (int j = 0; j < 4; ++j)
      b_h[j] = *(const bf16x8*)(sm + bb + rdoB + j * 1024);
    __builtin_amdgcn_s_setprio(1);
    #pragma unroll
    for (int i = 0; i < 4; ++i)
      #pragma unroll
      for (int j = 0; j < 4; ++j)
        acc[i][j] = MFMA(a_h[i], b_h[j], acc[i][j]);
    __builtin_amdgcn_s_setprio(0);
  }
}

// ---------------- QKV projection (1-term) ----------------------------------
__global__ __launch_bounds__(256) void k_gemm_qkv(
    const u16* __restrict__ Ah, const u16* __restrict__ Bh,
    u16* __restrict__ Qb, u16* __restrict__ Kb, u16* __restrict__ Vt) {
  __shared__ __align__(1024) char sm[32768];
  const int tid = threadIdx.x, lane = tid & 63, wid = tid >> 6;
  const int x = lane & 15, h = lane >> 4;
  const int wr = wid >> 1, wc = wid & 1;
  const int rowA = blockIdx.x * 128, rowB = blockIdx.y * 128;
  f32x4 acc[4][4] = {};
  gemm_core(Ah, Bh, sm, rowA, rowB, tid, acc);

  #pragma unroll
  for (int i = 0; i < 4; ++i)
    #pragma unroll
    for (int j = 0; j < 4; ++j) {
      const int n = rowB + wc * 64 + j * 16 + x;
      const int which = n >> 9;
      const int hh = (n >> 6) & 7, d = n & 63;
      const int m0 = rowA + wr * 64 + i * 16 + h * 4;
      const int b = m0 >> 11, is0 = m0 & 2047;
      if (which == 0) {
        #pragma unroll
        for (int r = 0; r < 4; ++r) {
          const size_t idx = ((size_t)((b * 8 + hh) * 2048 + is0 + r)) * 64 + d;
          Qb[idx] = f2bf(acc[i][j][r] * QSCALE);
        }
      } else if (which == 1) {
        #pragma unroll
        for (int r = 0; r < 4; ++r) {
          const size_t idx = ((size_t)((b * 8 + hh) * 2048 + is0 + r)) * 64 + d;
          Kb[idx] = f2bf(acc[i][j][r]);
        }
      } else {
        s16x4 vv;
        #pragma unroll
        for (int r = 0; r < 4; ++r) vv[r] = (short)f2bf(acc[i][j][r]);
        *(s16x4*)&Vt[((size_t)((b * 8 + hh) * 64 + d)) * 2048 + is0] = vv;
      }
    }
}

// ---------------- output projection with fused split-KV combine ------------
__global__ __launch_bounds__(256) void k_gemm_out(
    const u16* __restrict__ OP, const float* __restrict__ Mm,
    const float* __restrict__ Sm, const u16* __restrict__ Bh,
    const float* __restrict__ bias, float* __restrict__ out) {
  __shared__ __align__(1024) char sm[32768];
  const int tid = threadIdx.x, lane = tid & 63, wid = tid >> 6;
  const int x = lane & 15, h = lane >> 4;
  const int wr = wid >> 1, wc = wid & 1;
  const int rowA = blockIdx.x * 128, rowB = blockIdx.y * 128;

  const int d0 = tid * 16;
  const int lg0 = d0 ^ (((d0 >> 7) & 7) << 4);
  const int srow = lg0 >> 6;
  const int scol = (lg0 & 63) >> 1;
  const int swk = ((lane >> 1) & 7) << 4;
  const int rdoA = ((wr * 64 + x) * 64 + h * 16) ^ swk;
  const int rdoB = (((wc * 64 + x) * 64 + h * 16) ^ swk) + 8192;

  int bseq[2], srw[2];
  #pragma unroll
  for (int r = 0; r < 2; ++r) {
    const int m = rowA + r * 64 + srow;
    bseq[r] = (m >> 11) * 8;        // b*8
    srw[r] = m & 2047;              // seqrow
  }

  // ---- precompute merge weights for both staged rows x all 8 heads
  float w1p[2][8], w2p[2][8];
  #pragma unroll
  for (int r = 0; r < 2; ++r)
    #pragma unroll
    for (int hd = 0; hd < 8; ++hd) {
      const int rb = (bseq[r] + hd) * 2048 + srw[r];
      const float m1 = Mm[rb], m2 = Mm[65536 + rb];
      const float s1 = Sm[rb], s2 = Sm[65536 + rb];
      const float mm = fmaxf(m1, m2);
      const float a1 = fexp2(m1 - mm), a2 = fexp2(m2 - mm);
      const float inv = 1.0f / (s1 * a1 + s2 * a2);
      w1p[r][hd] = a1 * inv; w2p[r][hd] = a2 * inv;
    }

  f32x4 acc[4][4] = {};

  auto stageA = [&](int kt, char* buf) {
    const int head = kt >> 1;                  // static under unroll
    const int dd = (kt & 1) * 32 + scol;
    #pragma unroll
    for (int r = 0; r < 2; ++r) {
      const int rb = (bseq[r] + head) * 2048 + srw[r];
      const float w1 = w1p[r][head], w2 = w2p[r][head];
      bf16x8 p1 = *(const bf16x8*)&OP[(size_t)rb * 64 + dd];
      bf16x8 p2 = *(const bf16x8*)&OP[4194304 + (size_t)rb * 64 + dd];
      union { int w[4]; bf16x8 v; } uu;
      #pragma unroll
      for (int q = 0; q < 4; ++q) {
        float lo = bf2f((u16)p1[2 * q]) * w1 + bf2f((u16)p2[2 * q]) * w2;
        float hi = bf2f((u16)p1[2 * q + 1]) * w1 + bf2f((u16)p2[2 * q + 1]) * w2;
        uu.w[q] = cvtpk(lo, hi);
      }
      *(bf16x8*)(buf + r * 4096 + d0) = uu.v;
    }
  };

  {  // prologue: A(0) merge-stage + B(0) gld16 into buf0
    stageA(0, sm);
    #pragma unroll
    for (int r = 0; r < 2; ++r) {
      const size_t gb = (size_t)(rowB + r * 64 + srow) * 512 + scol;
      gld16(Bh + gb, (u16*)(sm + 8192 + r * 4096 + d0));
    }
    asm volatile("s_waitcnt lgkmcnt(0)" ::: "memory");
    __builtin_amdgcn_sched_barrier(0);
  }

  #pragma unroll
  for (int kt = 0; kt < 16; ++kt) {
    const int bb = (kt & 1) * 16384;
    asm volatile("s_barrier" ::: "memory");       // alt buf free
    if (kt < 15) {
      char* buf = sm + (16384 - bb);
      const int kofs = (kt + 1) * 32;
      #pragma unroll
      for (int r = 0; r < 2; ++r) {
        const size_t gb = (size_t)(rowB + r * 64 + srow) * 512 + kofs + scol;
        gld16(Bh + gb, (u16*)(buf + 8192 + r * 4096 + d0));
      }
      stageA(kt + 1, buf);                        // OP loads auto-waited
      asm volatile("s_waitcnt vmcnt(2)" ::: "memory");   // B(kt) landed
      asm volatile("s_waitcnt lgkmcnt(0)" ::: "memory"); // A writes retired
      __builtin_amdgcn_sched_barrier(0);
    } else {
      asm volatile("s_waitcnt vmcnt(0)" ::: "memory");
    }
    asm volatile("s_barrier" ::: "memory");       // tile kt published

    bf16x8 a_h[4], b_h[4];
    #pragma unroll
    for (int i = 0; i < 4; ++i)
      a_h[i] = *(const bf16x8*)(sm + bb + rdoA + i * 1024);
    #pragma unroll
    for (int j = 0; j < 4; ++j)
      b_h[j] = *(const bf16x8*)(sm + bb + rdoB + j * 1024);
    __builtin_amdgcn_s_setprio(1);
    #pragma unroll
    for (int i = 0; i < 4; ++i)
      #pragma unroll
      for (int j = 0; j < 4; ++j)
        acc[i][j] = MFMA(a_h[i], b_h[j], acc[i][j]);
    __builtin_amdgcn_s_setprio(0);
  }

  #pragma unroll
  for (int i = 0; i < 4; ++i)
    #pragma unroll
    for (int j = 0; j < 4; ++j) {
      const int n = rowB + wc * 64 + j * 16 + x;
      #pragma unroll
      for (int r = 0; r < 4; ++r) {
        const int m = rowA + wr * 64 + i * 16 + h * 4 + r;
        out[(size_t)m * 512 + n] = acc[i][j][r] + bias[n];
      }
    }
}

// ---------------- flash attention, split-KV half, 8-wave blocks -------------
// (R14 body: ~51us, 16 waves/CU structural ceiling)
__global__ __launch_bounds__(512, 2) void k_attn(
    const u16* __restrict__ Qb,
    const u16* __restrict__ Kb, const u16* __restrict__ Vt,
    u16* __restrict__ OP,          // [2][32*2048*64] bf16 (+half*4194304)
    float* __restrict__ Mm,        // [2][65536]
    float* __restrict__ Sm) {      // [2][65536]
  __shared__ __align__(1024) char sm[65536];
  const int tid = threadIdx.x, wid = tid >> 6, lane = tid & 63;
  const int x = lane & 15, h = lane >> 4;

  const int fid = blockIdx.x;
  const int l = (fid & 7) * 64 + (fid >> 3);
  const int half = l & 1, qb = (l >> 1) & 7, bh = l >> 4;

  const size_t base = (size_t)bh * 2048 * 64;
  const int qr0 = qb * 256 + wid * 32;
  const size_t kv0 = (size_t)half * 1024;

  bf16x8 qh[2][2];
  #pragma unroll
  for (int g = 0; g < 2; ++g) {
    const size_t rq = base + (size_t)(qr0 + g * 16 + x) * 64 + h * 8;
    #pragma unroll
    for (int ks = 0; ks < 2; ++ks)
      qh[g][ks] = *(const bf16x8*)&Qb[rq + ks * 32];
  }

  bf16x8 ones;
  #pragma unroll
  for (int j = 0; j < 8; ++j) ones[j] = (short)0x3F80;

  const int db = tid * 16;
  const int lg = db ^ (((db >> 7) & 7) << 4);
  const int sks  = db >> 12;
  const int srow = (lg >> 6) & 63;
  const int scb  = (lg & 63) >> 1;
  const size_t offK = (size_t)srow * 64 + sks * 32 + scb;
  const size_t offV = (size_t)srow * 2048 + sks * 32 + scb;

  const int swk = ((lane >> 1) & 7) << 4;
  const int rdo = (x * 64 + h * 16) ^ swk;
  char* const pb = sm + 32768 + wid * 4096;
  const int pxor = (x & 7) << 4;
  const int prow = x * 128;

  float mrun[2] = {-INFINITY, -INFINITY};
  f32x4 o[2][4] = {};
  f32x4 os[2] = {};

  {
    gld16(Kb + base + kv0 * 64 + offK, (u16*)(sm + db));
    gld16(Vt + base + kv0 + offV,      (u16*)(sm + 8192 + db));
  }

  for (int kv = 0; kv < 16; ++kv) {
    const int bb = (kv & 1) * 16384;
    __builtin_amdgcn_s_barrier();
    if (kv < 15) {
      const size_t kvb = kv0 + (size_t)(kv + 1) * 64;
      char* buf = sm + (16384 - bb);
      gld16(Kb + base + kvb * 64 + offK, (u16*)(buf + db));
      gld16(Vt + base + kvb + offV,      (u16*)(buf + 8192 + db));
      asm volatile("s_waitcnt vmcnt(2)" ::: "memory");
    } else {
      asm volatile("s_waitcnt vmcnt(0)" ::: "memory");
    }
    __builtin_amdgcn_s_barrier();

    const char* smb = sm + bb + rdo;

    f32x4 s[2][4] = {};
    __builtin_amdgcn_s_setprio(1);
    #pragma unroll
    for (int c = 0; c < 4; ++c)
      #pragma unroll
      for (int ks = 0; ks < 2; ++ks) {
        bf16x8 kb_ = *(const bf16x8*)(smb + ks * 4096 + c * 1024);
        s[0][c] = MFMA(kb_, qh[0][ks], s[0][c]);
        s[1][c] = MFMA(kb_, qh[1][ks], s[1][c]);
      }
    __builtin_amdgcn_s_setprio(0);

    float pm[2];
    #pragma unroll
    for (int g = 0; g < 2; ++g) {
      float m0 = fmaxf(fmaxf(s[g][0][0], s[g][0][1]), s[g][0][2]);
      float m1 = fmaxf(fmaxf(s[g][0][3], s[g][1][0]), s[g][1][1]);
      float m2 = fmaxf(fmaxf(s[g][1][2], s[g][1][3]), s[g][2][0]);
      float m3 = fmaxf(fmaxf(s[g][2][1], s[g][2][2]), s[g][2][3]);
      float m4 = fmaxf(fmaxf(s[g][3][0], s[g][3][1]), s[g][3][2]);
      float m5 = fmaxf(fmaxf(m0, m1), m2);
      float p  = fmaxf(fmaxf(fmaxf(m3, m4), s[g][3][3]), m5);
      p = fmaxf(p, __shfl_xor(p, 16, 64));
      p = fmaxf(p, __shfl_xor(p, 32, 64));
      pm[g] = p;
    }

    if (__any((pm[0] > mrun[0] + 7.0f) || (pm[1] > mrun[1] + 7.0f))) {
      #pragma unroll
      for (int g = 0; g < 2; ++g) {
        float mnew = fmaxf(mrun[g], pm[g]);
        float scl = fexp2(mrun[g] - mnew);
        mrun[g] = mnew;
        #pragma unroll
        for (int r = 0; r < 4; ++r) {
          float sq = u2f((unsigned)__builtin_amdgcn_ds_bpermute(
              (20 * h + r) * 4, (int)f2u(scl)));
          os[g][r] *= sq;
          #pragma unroll
          for (int dg = 0; dg < 4; ++dg) o[g][dg][r] *= sq;
        }
      }
    }

    #pragma unroll
    for (int g = 0; g < 2; ++g)
      #pragma unroll
      for (int c = 0; c < 4; ++c) {
        int w0 = cvtpk(fexp2(s[g][c][0] - mrun[g]),
                       fexp2(s[g][c][1] - mrun[g]));
        int w1 = cvtpk(fexp2(s[g][c][2] - mrun[g]),
                       fexp2(s[g][c][3] - mrun[g]));
        int* dst = (int*)(pb + g * 2048 + prow + ((c * 32 + h * 8) ^ pxor));
        dst[0] = w0; dst[1] = w1;
      }

    __builtin_amdgcn_s_setprio(1);
    #pragma unroll
    for (int ch = 0; ch < 2; ++ch) {
      bf16x8 pa0 = *(const bf16x8*)(pb + prow +
                                    ((ch * 64 + h * 16) ^ pxor));
      bf16x8 pa1 = *(const bf16x8*)(pb + 2048 + prow +
                                    ((ch * 64 + h * 16) ^ pxor));
      os[0] = MFMA(pa0, ones, os[0]);
      os[1] = MFMA(pa1, ones, os[1]);
      #pragma unroll
      for (int dg = 0; dg < 4; ++dg) {
        bf16x8 vb = *(const bf16x8*)(smb + 8192 + ch * 4096 + dg * 1024);
        o[0][dg] = MFMA(pa0, vb, o[0][dg]);
        o[1][dg] = MFMA(pa1, vb, o[1][dg]);
      }
    }
    __builtin_amdgcn_s_setprio(0);
  }

  u16* op = OP + (size_t)half * 4194304 + ((size_t)(bh * 2048 + qr0)) * 64;
  #pragma unroll
  for (int g = 0; g < 2; ++g) {
    #pragma unroll
    for (int r = 0; r < 4; ++r) {
      const int row = g * 16 + h * 4 + r;
      #pragma unroll
      for (int dg = 0; dg < 4; ++dg)
        op[(size_t)row * 64 + dg * 16 + x] = f2bf(o[g][dg][r]);
      if (x == 0)
        Sm[half * 65536 + bh * 2048 + qr0 + g * 16 + h * 4 + r] = os[g][r];
    }
    if (h == 0)
      Mm[half * 65536 + bh * 2048 + qr0 + g * 16 + x] = mrun[g];
  }
}

// ---------------------------------------------------------------------------
extern "C" void kernel_launch(void* const* d_in, const int* in_sizes, int n_in,
                              void* d_out, int out_size, void* d_ws, size_t ws_size,
                              hipStream_t stream) {
  const float* x    = (const float*)d_in[0];
  const float* wqkv = (const float*)d_in[1];
  const float* wout = (const float*)d_in[2];
  const float* bout = (const float*)d_in[3];
  float* out = (float*)d_out;

  char* w = (char*)d_ws;
  u16* xh  = (u16*)(w + 0);           // 8192x512 bf16 (dead after qkv)
  u16* wqh = (u16*)(w + 16777216);    // WqkvT [1536][512] (dead after qkv)
  u16* woh = (u16*)(w + 19922944);    // WoutT [512][512] (live to end)
  u16* Qb  = (u16*)(w + 20971520);    // [32][2048][64] bf16 (pre-scaled)
  u16* Kb  = (u16*)(w + 37748736);    // [32][2048][64] bf16
  u16* Vt  = (u16*)(w + 46137344);    // [32][64][2048] bf16
  // Split-KV partials (alias dead phase-1 regions):
  u16*   OP = (u16*)(w + 0);          // [2][4194304] bf16 = 16MB
  float* Mm = (float*)(w + 16777216); // [2][65536] f32
  float* Sm = (float*)(w + 17301504); // [2][65536] f32 (ends < woh)

  k_prep<<<4352, 256, 0, stream>>>(x, xh, wqkv, wqh, wout, woh);
  k_gemm_qkv<<<dim3(64, 12), 256, 0, stream>>>(xh, wqh, Qb, Kb, Vt);
  k_attn<<<512, 512, 0, stream>>>(Qb, Kb, Vt, OP, Mm, Sm);
  k_gemm_out<<<dim3(64, 4), 256, 0, stream>>>(OP, Mm, Sm, woh, bout, out);
}

// Round 20
// 92.219 us; speedup vs baseline: 4.1570x; 1.0098x over previous
//
#include <hip/hip_runtime.h>
#include <hip/hip_bf16.h>
#include <math.h>
#include <stdint.h>

// ---------------------------------------------------------------------------
// Attention (B=4, N=2048, D=512, H=8, Dh=64) for MI355X.
// Precision plan (threshold 6.48e-3; measured floor 1.95e-3):
//   x@Wqkv: 1-term bf16.  QK^T: bf16.  PV: bf16 P,V.  out GEMM 1-term with
//   fused exact log2-domain split-KV merge on the A-operand.
// R20: (1) x-cast fused into k_gemm_qkv (A reg-staged: f32 loads -> cvt_pk
// -> ds_write; xh round-trip eliminated; k_prep = weight transposes only);
// (2) loads-first ordering in both GEMM staging paths so the compiler's
// A-reg wait is vmcnt(2), keeping the B gld16 prefetch alive across the
// barrier (was silently drained to vmcnt(0) by in-order completion).
// k_attn unchanged (R14 body, structural plateau at 16 waves/CU).
// ---------------------------------------------------------------------------

typedef unsigned short u16;
typedef __attribute__((ext_vector_type(4))) float f32x4;
typedef __attribute__((ext_vector_type(8))) short bf16x8;   // 8 bf16 = 4 VGPRs
typedef __attribute__((ext_vector_type(4))) short s16x4;

#define AS1 __attribute__((address_space(1)))
#define AS3 __attribute__((address_space(3)))
#define MFMA(a, b, c) __builtin_amdgcn_mfma_f32_16x16x32_bf16(a, b, c, 0, 0, 0)
#define QSCALE 0.180336880f   /* 0.125 * log2(e): logits in log2 domain */

__device__ __forceinline__ u16 f2bf(float f) {
  union { float f; unsigned u; } v; v.f = f;
  unsigned r = v.u + 0x7FFFu + ((v.u >> 16) & 1u);   // RNE
  return (u16)(r >> 16);
}
__device__ __forceinline__ float bf2f(u16 b) {
  union { unsigned u; float f; } v; v.u = ((unsigned)b) << 16; return v.f;
}
__device__ __forceinline__ void gld16(const u16* g, u16* l) {
  __builtin_amdgcn_global_load_lds((const AS1 void*)g, (AS3 void*)l, 16, 0, 0);
}
__device__ __forceinline__ float u2f(unsigned u) {
  union { unsigned u; float f; } v; v.u = u; return v.f;
}
__device__ __forceinline__ unsigned f2u(float f) {
  union { float f; unsigned u; } v; v.f = f; return v.u;
}
__device__ __forceinline__ int cvtpk(float lo, float hi) {
  int r; asm("v_cvt_pk_bf16_f32 %0, %1, %2" : "=v"(r) : "v"(lo), "v"(hi));
  return r;
}
__device__ __forceinline__ float fexp2(float x) {
  float r; asm("v_exp_f32 %0, %1" : "=v"(r) : "v"(x));
  return r;
}

// ---------------- prep: weight transposes only (64x64 LDS tiles) ------------
// blocks 0..191: wqkv [512][1536] -> [1536][512]; 192..255: wout transpose.
__global__ __launch_bounds__(256) void k_prep(
    const float* __restrict__ wqkv, u16* __restrict__ wqh,
    const float* __restrict__ wout, u16* __restrict__ woh) {
  const int bid = blockIdx.x, tid = threadIdx.x;
  __shared__ u16 lds[64][66];
  const float* src; u16* dst; int N, n0, k0;
  if (bid < 192) {
    src = wqkv; dst = wqh; N = 1536;
    n0 = (bid % 24) * 64; k0 = (bid / 24) * 64;
  } else {
    const int b3 = bid - 192;
    src = wout; dst = woh; N = 512;
    n0 = (b3 & 7) * 64; k0 = (b3 >> 3) * 64;
  }
  const int c = tid & 63, q = tid >> 6;
  #pragma unroll
  for (int s = 0; s < 16; ++s) {          // coalesced f32 row reads
    const int kr = q * 16 + s;
    lds[c][kr] = f2bf(src[(size_t)(k0 + kr) * N + n0 + c]);
  }
  __syncthreads();
  #pragma unroll
  for (int s = 0; s < 16; ++s) {          // coalesced bf16 row writes
    const int nr = q * 16 + s;
    dst[(size_t)(n0 + nr) * 512 + k0 + c] = lds[nr][c];
  }
}

// ---------------- QKV projection: A = f32 x (fused cast), B = bf16 WqkvT ----
// C[128x128], K=512, BK=32, dbuf.  A: f32 reg loads (issued FIRST) ->
// cvt_pk -> ds_write (linear dest, same image as gld16).  B: gld16 (issued
// after A loads so the A-reg wait = vmcnt(2), B prefetch stays in flight).
__global__ __launch_bounds__(256) void k_gemm_qkv(
    const float* __restrict__ xf, const u16* __restrict__ Bh,
    u16* __restrict__ Qb, u16* __restrict__ Kb, u16* __restrict__ Vt) {
  __shared__ __align__(1024) char sm[32768];
  const int tid = threadIdx.x, lane = tid & 63, wid = tid >> 6;
  const int x = lane & 15, h = lane >> 4;
  const int wr = wid >> 1, wc = wid & 1;
  const int rowA = blockIdx.x * 128, rowB = blockIdx.y * 128;

  const int d0 = tid * 16;
  const int lg0 = d0 ^ (((d0 >> 7) & 7) << 4);
  const int srow = lg0 >> 6;
  const int scol = (lg0 & 63) >> 1;
  const int swk = ((lane >> 1) & 7) << 4;
  const int rdoA = ((wr * 64 + x) * 64 + h * 16) ^ swk;
  const int rdoB = (((wc * 64 + x) * 64 + h * 16) ^ swk) + 8192;

  f32x4 acc[4][4] = {};

  {  // prologue: A(0) f32 loads -> B(0) gld16 -> cvt+write
    f32x4 a0[2], a1[2];
    #pragma unroll
    for (int r = 0; r < 2; ++r) {
      const float* src = xf + (size_t)(rowA + r * 64 + srow) * 512 + scol;
      a0[r] = *(const f32x4*)src;
      a1[r] = *(const f32x4*)(src + 4);
    }
    #pragma unroll
    for (int r = 0; r < 2; ++r) {
      const size_t gb = (size_t)(rowB + r * 64 + srow) * 512 + scol;
      gld16(Bh + gb, (u16*)(sm + 8192 + r * 4096 + d0));
    }
    #pragma unroll
    for (int r = 0; r < 2; ++r) {
      union { int w[4]; bf16x8 v; } uu;
      uu.w[0] = cvtpk(a0[r][0], a0[r][1]);
      uu.w[1] = cvtpk(a0[r][2], a0[r][3]);
      uu.w[2] = cvtpk(a1[r][0], a1[r][1]);
      uu.w[3] = cvtpk(a1[r][2], a1[r][3]);
      *(bf16x8*)(sm + r * 4096 + d0) = uu.v;
    }
    asm volatile("s_waitcnt lgkmcnt(0)" ::: "memory");
    __builtin_amdgcn_sched_barrier(0);
  }

  for (int kt = 0; kt < 16; ++kt) {
    const int bb = (kt & 1) * 16384;
    asm volatile("s_barrier" ::: "memory");       // alt buf free
    if (kt < 15) {
      char* buf = sm + (16384 - bb);
      const int kofs = (kt + 1) * 32;
      f32x4 a0[2], a1[2];
      #pragma unroll
      for (int r = 0; r < 2; ++r) {               // A f32 loads FIRST
        const float* src = xf + (size_t)(rowA + r * 64 + srow) * 512 +
                           kofs + scol;
        a0[r] = *(const f32x4*)src;
        a1[r] = *(const f32x4*)(src + 4);
      }
      #pragma unroll
      for (int r = 0; r < 2; ++r) {               // then B gld16 (newest)
        const size_t gb = (size_t)(rowB + r * 64 + srow) * 512 + kofs + scol;
        gld16(Bh + gb, (u16*)(buf + 8192 + r * 4096 + d0));
      }
      #pragma unroll
      for (int r = 0; r < 2; ++r) {               // cvt+write (waits vmcnt(2))
        union { int w[4]; bf16x8 v; } uu;
        uu.w[0] = cvtpk(a0[r][0], a0[r][1]);
        uu.w[1] = cvtpk(a0[r][2], a0[r][3]);
        uu.w[2] = cvtpk(a1[r][0], a1[r][1]);
        uu.w[3] = cvtpk(a1[r][2], a1[r][3]);
        *(bf16x8*)(buf + r * 4096 + d0) = uu.v;
      }
      asm volatile("s_waitcnt vmcnt(2)" ::: "memory");   // B(kt) landed
      asm volatile("s_waitcnt lgkmcnt(0)" ::: "memory"); // A writes retired
      __builtin_amdgcn_sched_barrier(0);
    } else {
      asm volatile("s_waitcnt vmcnt(0)" ::: "memory");
    }
    asm volatile("s_barrier" ::: "memory");       // tile kt published

    bf16x8 a_h[4], b_h[4];
    #pragma unroll
    for (int i = 0; i < 4; ++i)
      a_h[i] = *(const bf16x8*)(sm + bb + rdoA + i * 1024);
    #pragma unroll
    for (int j = 0; j < 4; ++j)
      b_h[j] = *(const bf16x8*)(sm + bb + rdoB + j * 1024);
    __builtin_amdgcn_s_setprio(1);
    #pragma unroll
    for (int i = 0; i < 4; ++i)
      #pragma unroll
      for (int j = 0; j < 4; ++j)
        acc[i][j] = MFMA(a_h[i], b_h[j], acc[i][j]);
    __builtin_amdgcn_s_setprio(0);
  }

  #pragma unroll
  for (int i = 0; i < 4; ++i)
    #pragma unroll
    for (int j = 0; j < 4; ++j) {
      const int n = rowB + wc * 64 + j * 16 + x;
      const int which = n >> 9;
      const int hh = (n >> 6) & 7, d = n & 63;
      const int m0 = rowA + wr * 64 + i * 16 + h * 4;
      const int b = m0 >> 11, is0 = m0 & 2047;
      if (which == 0) {
        #pragma unroll
        for (int r = 0; r < 4; ++r) {
          const size_t idx = ((size_t)((b * 8 + hh) * 2048 + is0 + r)) * 64 + d;
          Qb[idx] = f2bf(acc[i][j][r] * QSCALE);
        }
      } else if (which == 1) {
        #pragma unroll
        for (int r = 0; r < 4; ++r) {
          const size_t idx = ((size_t)((b * 8 + hh) * 2048 + is0 + r)) * 64 + d;
          Kb[idx] = f2bf(acc[i][j][r]);
        }
      } else {
        s16x4 vv;
        #pragma unroll
        for (int r = 0; r < 4; ++r) vv[r] = (short)f2bf(acc[i][j][r]);
        *(s16x4*)&Vt[((size_t)((b * 8 + hh) * 64 + d)) * 2048 + is0] = vv;
      }
    }
}

// ---------------- output projection with fused split-KV combine ------------
// OP reg loads FIRST, then B gld16, then merge+write (A-reg wait = vmcnt(2)).
__global__ __launch_bounds__(256) void k_gemm_out(
    const u16* __restrict__ OP, const float* __restrict__ Mm,
    const float* __restrict__ Sm, const u16* __restrict__ Bh,
    const float* __restrict__ bias, float* __restrict__ out) {
  __shared__ __align__(1024) char sm[32768];
  const int tid = threadIdx.x, lane = tid & 63, wid = tid >> 6;
  const int x = lane & 15, h = lane >> 4;
  const int wr = wid >> 1, wc = wid & 1;
  const int rowA = blockIdx.x * 128, rowB = blockIdx.y * 128;

  const int d0 = tid * 16;
  const int lg0 = d0 ^ (((d0 >> 7) & 7) << 4);
  const int srow = lg0 >> 6;
  const int scol = (lg0 & 63) >> 1;
  const int swk = ((lane >> 1) & 7) << 4;
  const int rdoA = ((wr * 64 + x) * 64 + h * 16) ^ swk;
  const int rdoB = (((wc * 64 + x) * 64 + h * 16) ^ swk) + 8192;

  int bseq[2], srw[2];
  #pragma unroll
  for (int r = 0; r < 2; ++r) {
    const int m = rowA + r * 64 + srow;
    bseq[r] = (m >> 11) * 8;        // b*8
    srw[r] = m & 2047;              // seqrow
  }

  // ---- precompute merge weights for both staged rows x all 8 heads
  float w1p[2][8], w2p[2][8];
  #pragma unroll
  for (int r = 0; r < 2; ++r)
    #pragma unroll
    for (int hd = 0; hd < 8; ++hd) {
      const int rb = (bseq[r] + hd) * 2048 + srw[r];
      const float m1 = Mm[rb], m2 = Mm[65536 + rb];
      const float s1 = Sm[rb], s2 = Sm[65536 + rb];
      const float mm = fmaxf(m1, m2);
      const float a1 = fexp2(m1 - mm), a2 = fexp2(m2 - mm);
      const float inv = 1.0f / (s1 * a1 + s2 * a2);
      w1p[r][hd] = a1 * inv; w2p[r][hd] = a2 * inv;
    }

  f32x4 acc[4][4] = {};

  // load part (regs) and merge+write part, split so B can issue between
  auto loadA = [&](int kt, bf16x8 (&p1)[2], bf16x8 (&p2)[2]) {
    const int head = kt >> 1;
    const int dd = (kt & 1) * 32 + scol;
    #pragma unroll
    for (int r = 0; r < 2; ++r) {
      const int rb = (bseq[r] + head) * 2048 + srw[r];
      p1[r] = *(const bf16x8*)&OP[(size_t)rb * 64 + dd];
      p2[r] = *(const bf16x8*)&OP[4194304 + (size_t)rb * 64 + dd];
    }
  };
  auto writeA = [&](int kt, const bf16x8 (&p1)[2], const bf16x8 (&p2)[2],
                    char* buf) {
    const int head = kt >> 1;
    #pragma unroll
    for (int r = 0; r < 2; ++r) {
      const float w1 = w1p[r][head], w2 = w2p[r][head];
      union { int w[4]; bf16x8 v; } uu;
      #pragma unroll
      for (int q = 0; q < 4; ++q) {
        float lo = bf2f((u16)p1[r][2 * q]) * w1 + bf2f((u16)p2[r][2 * q]) * w2;
        float hi = bf2f((u16)p1[r][2 * q + 1]) * w1 +
                   bf2f((u16)p2[r][2 * q + 1]) * w2;
        uu.w[q] = cvtpk(lo, hi);
      }
      *(bf16x8*)(buf + r * 4096 + d0) = uu.v;
    }
  };

  {  // prologue: A(0) loads -> B(0) gld16 -> merge+write
    bf16x8 p1[2], p2[2];
    loadA(0, p1, p2);
    #pragma unroll
    for (int r = 0; r < 2; ++r) {
      const size_t gb = (size_t)(rowB + r * 64 + srow) * 512 + scol;
      gld16(Bh + gb, (u16*)(sm + 8192 + r * 4096 + d0));
    }
    writeA(0, p1, p2, sm);
    asm volatile("s_waitcnt lgkmcnt(0)" ::: "memory");
    __builtin_amdgcn_sched_barrier(0);
  }

  #pragma unroll
  for (int kt = 0; kt < 16; ++kt) {
    const int bb = (kt & 1) * 16384;
    asm volatile("s_barrier" ::: "memory");       // alt buf free
    if (kt < 15) {
      char* buf = sm + (16384 - bb);
      const int kofs = (kt + 1) * 32;
      bf16x8 p1[2], p2[2];
      loadA(kt + 1, p1, p2);                      // OP reg loads FIRST
      #pragma unroll
      for (int r = 0; r < 2; ++r) {               // then B gld16 (newest)
        const size_t gb = (size_t)(rowB + r * 64 + srow) * 512 + kofs + scol;
        gld16(Bh + gb, (u16*)(buf + 8192 + r * 4096 + d0));
      }
      writeA(kt + 1, p1, p2, buf);                // waits vmcnt(2) via regs
      asm volatile("s_waitcnt vmcnt(2)" ::: "memory");   // B(kt) landed
      asm volatile("s_waitcnt lgkmcnt(0)" ::: "memory"); // A writes retired
      __builtin_amdgcn_sched_barrier(0);
    } else {
      asm volatile("s_waitcnt vmcnt(0)" ::: "memory");
    }
    asm volatile("s_barrier" ::: "memory");       // tile kt published

    bf16x8 a_h[4], b_h[4];
    #pragma unroll
    for (int i = 0; i < 4; ++i)
      a_h[i] = *(const bf16x8*)(sm + bb + rdoA + i * 1024);
    #pragma unroll
    for (int j = 0; j < 4; ++j)
      b_h[j] = *(const bf16x8*)(sm + bb + rdoB + j * 1024);
    __builtin_amdgcn_s_setprio(1);
    #pragma unroll
    for (int i = 0; i < 4; ++i)
      #pragma unroll
      for (int j = 0; j < 4; ++j)
        acc[i][j] = MFMA(a_h[i], b_h[j], acc[i][j]);
    __builtin_amdgcn_s_setprio(0);
  }

  #pragma unroll
  for (int i = 0; i < 4; ++i)
    #pragma unroll
    for (int j = 0; j < 4; ++j) {
      const int n = rowB + wc * 64 + j * 16 + x;
      #pragma unroll
      for (int r = 0; r < 4; ++r) {
        const int m = rowA + wr * 64 + i * 16 + h * 4 + r;
        out[(size_t)m * 512 + n] = acc[i][j][r] + bias[n];
      }
    }
}

// ---------------- flash attention, split-KV half, 8-wave blocks -------------
// (R14 body: ~51us, 16 waves/CU structural ceiling)
__global__ __launch_bounds__(512, 2) void k_attn(
    const u16* __restrict__ Qb,
    const u16* __restrict__ Kb, const u16* __restrict__ Vt,
    u16* __restrict__ OP,          // [2][32*2048*64] bf16 (+half*4194304)
    float* __restrict__ Mm,        // [2][65536]
    float* __restrict__ Sm) {      // [2][65536]
  __shared__ __align__(1024) char sm[65536];
  const int tid = threadIdx.x, wid = tid >> 6, lane = tid & 63;
  const int x = lane & 15, h = lane >> 4;

  const int fid = blockIdx.x;
  const int l = (fid & 7) * 64 + (fid >> 3);
  const int half = l & 1, qb = (l >> 1) & 7, bh = l >> 4;

  const size_t base = (size_t)bh * 2048 * 64;
  const int qr0 = qb * 256 + wid * 32;
  const size_t kv0 = (size_t)half * 1024;

  bf16x8 qh[2][2];
  #pragma unroll
  for (int g = 0; g < 2; ++g) {
    const size_t rq = base + (size_t)(qr0 + g * 16 + x) * 64 + h * 8;
    #pragma unroll
    for (int ks = 0; ks < 2; ++ks)
      qh[g][ks] = *(const bf16x8*)&Qb[rq + ks * 32];
  }

  bf16x8 ones;
  #pragma unroll
  for (int j = 0; j < 8; ++j) ones[j] = (short)0x3F80;

  const int db = tid * 16;
  const int lg = db ^ (((db >> 7) & 7) << 4);
  const int sks  = db >> 12;
  const int srow = (lg >> 6) & 63;
  const int scb  = (lg & 63) >> 1;
  const size_t offK = (size_t)srow * 64 + sks * 32 + scb;
  const size_t offV = (size_t)srow * 2048 + sks * 32 + scb;

  const int swk = ((lane >> 1) & 7) << 4;
  const int rdo = (x * 64 + h * 16) ^ swk;
  char* const pb = sm + 32768 + wid * 4096;
  const int pxor = (x & 7) << 4;
  const int prow = x * 128;

  float mrun[2] = {-INFINITY, -INFINITY};
  f32x4 o[2][4] = {};
  f32x4 os[2] = {};

  {
    gld16(Kb + base + kv0 * 64 + offK, (u16*)(sm + db));
    gld16(Vt + base + kv0 + offV,      (u16*)(sm + 8192 + db));
  }

  for (int kv = 0; kv < 16; ++kv) {
    const int bb = (kv & 1) * 16384;
    __builtin_amdgcn_s_barrier();
    if (kv < 15) {
      const size_t kvb = kv0 + (size_t)(kv + 1) * 64;
      char* buf = sm + (16384 - bb);
      gld16(Kb + base + kvb * 64 + offK, (u16*)(buf + db));
      gld16(Vt + base + kvb + offV,      (u16*)(buf + 8192 + db));
      asm volatile("s_waitcnt vmcnt(2)" ::: "memory");
    } else {
      asm volatile("s_waitcnt vmcnt(0)" ::: "memory");
    }
    __builtin_amdgcn_s_barrier();

    const char* smb = sm + bb + rdo;

    f32x4 s[2][4] = {};
    __builtin_amdgcn_s_setprio(1);
    #pragma unroll
    for (int c = 0; c < 4; ++c)
      #pragma unroll
      for (int ks = 0; ks < 2; ++ks) {
        bf16x8 kb_ = *(const bf16x8*)(smb + ks * 4096 + c * 1024);
        s[0][c] = MFMA(kb_, qh[0][ks], s[0][c]);
        s[1][c] = MFMA(kb_, qh[1][ks], s[1][c]);
      }
    __builtin_amdgcn_s_setprio(0);

    float pm[2];
    #pragma unroll
    for (int g = 0; g < 2; ++g) {
      float m0 = fmaxf(fmaxf(s[g][0][0], s[g][0][1]), s[g][0][2]);
      float m1 = fmaxf(fmaxf(s[g][0][3], s[g][1][0]), s[g][1][1]);
      float m2 = fmaxf(fmaxf(s[g][1][2], s[g][1][3]), s[g][2][0]);
      float m3 = fmaxf(fmaxf(s[g][2][1], s[g][2][2]), s[g][2][3]);
      float m4 = fmaxf(fmaxf(s[g][3][0], s[g][3][1]), s[g][3][2]);
      float m5 = fmaxf(fmaxf(m0, m1), m2);
      float p  = fmaxf(fmaxf(fmaxf(m3, m4), s[g][3][3]), m5);
      p = fmaxf(p, __shfl_xor(p, 16, 64));
      p = fmaxf(p, __shfl_xor(p, 32, 64));
      pm[g] = p;
    }

    if (__any((pm[0] > mrun[0] + 7.0f) || (pm[1] > mrun[1] + 7.0f))) {
      #pragma unroll
      for (int g = 0; g < 2; ++g) {
        float mnew = fmaxf(mrun[g], pm[g]);
        float scl = fexp2(mrun[g] - mnew);
        mrun[g] = mnew;
        #pragma unroll
        for (int r = 0; r < 4; ++r) {
          float sq = u2f((unsigned)__builtin_amdgcn_ds_bpermute(
              (20 * h + r) * 4, (int)f2u(scl)));
          os[g][r] *= sq;
          #pragma unroll
          for (int dg = 0; dg < 4; ++dg) o[g][dg][r] *= sq;
        }
      }
    }

    #pragma unroll
    for (int g = 0; g < 2; ++g)
      #pragma unroll
      for (int c = 0; c < 4; ++c) {
        int w0 = cvtpk(fexp2(s[g][c][0] - mrun[g]),
                       fexp2(s[g][c][1] - mrun[g]));
        int w1 = cvtpk(fexp2(s[g][c][2] - mrun[g]),
                       fexp2(s[g][c][3] - mrun[g]));
        int* dst = (int*)(pb + g * 2048 + prow + ((c * 32 + h * 8) ^ pxor));
        dst[0] = w0; dst[1] = w1;
      }

    __builtin_amdgcn_s_setprio(1);
    #pragma unroll
    for (int ch = 0; ch < 2; ++ch) {
      bf16x8 pa0 = *(const bf16x8*)(pb + prow +
                                    ((ch * 64 + h * 16) ^ pxor));
      bf16x8 pa1 = *(const bf16x8*)(pb + 2048 + prow +
                                    ((ch * 64 + h * 16) ^ pxor));
      os[0] = MFMA(pa0, ones, os[0]);
      os[1] = MFMA(pa1, ones, os[1]);
      #pragma unroll
      for (int dg = 0; dg < 4; ++dg) {
        bf16x8 vb = *(const bf16x8*)(smb + 8192 + ch * 4096 + dg * 1024);
        o[0][dg] = MFMA(pa0, vb, o[0][dg]);
        o[1][dg] = MFMA(pa1, vb, o[1][dg]);
      }
    }
    __builtin_amdgcn_s_setprio(0);
  }

  u16* op = OP + (size_t)half * 4194304 + ((size_t)(bh * 2048 + qr0)) * 64;
  #pragma unroll
  for (int g = 0; g < 2; ++g) {
    #pragma unroll
    for (int r = 0; r < 4; ++r) {
      const int row = g * 16 + h * 4 + r;
      #pragma unroll
      for (int dg = 0; dg < 4; ++dg)
        op[(size_t)row * 64 + dg * 16 + x] = f2bf(o[g][dg][r]);
      if (x == 0)
        Sm[half * 65536 + bh * 2048 + qr0 + g * 16 + h * 4 + r] = os[g][r];
    }
    if (h == 0)
      Mm[half * 65536 + bh * 2048 + qr0 + g * 16 + x] = mrun[g];
  }
}

// ---------------------------------------------------------------------------
extern "C" void kernel_launch(void* const* d_in, const int* in_sizes, int n_in,
                              void* d_out, int out_size, void* d_ws, size_t ws_size,
                              hipStream_t stream) {
  const float* x    = (const float*)d_in[0];
  const float* wqkv = (const float*)d_in[1];
  const float* wout = (const float*)d_in[2];
  const float* bout = (const float*)d_in[3];
  float* out = (float*)d_out;

  char* w = (char*)d_ws;
  u16* wqh = (u16*)(w + 16777216);    // WqkvT [1536][512] (dead after qkv)
  u16* woh = (u16*)(w + 19922944);    // WoutT [512][512] (live to end)
  u16* Qb  = (u16*)(w + 20971520);    // [32][2048][64] bf16 (pre-scaled)
  u16* Kb  = (u16*)(w + 37748736);    // [32][2048][64] bf16
  u16* Vt  = (u16*)(w + 46137344);    // [32][64][2048] bf16
  // Split-KV partials (alias dead regions):
  u16*   OP = (u16*)(w + 0);          // [2][4194304] bf16 = 16MB
  float* Mm = (float*)(w + 16777216); // [2][65536] f32 (aliases dead wqh after attn... wait: wqh dead after qkv, attn writes Mm -> ok)
  float* Sm = (float*)(w + 17301504); // [2][65536] f32 (ends < woh)

  k_prep<<<256, 256, 0, stream>>>(wqkv, wqh, wout, woh);
  k_gemm_qkv<<<dim3(64, 12), 256, 0, stream>>>(x, wqh, Qb, Kb, Vt);
  k_attn<<<512, 512, 0, stream>>>(Qb, Kb, Vt, OP, Mm, Sm);
  k_gemm_out<<<dim3(64, 4), 256, 0, stream>>>(OP, Mm, Sm, woh, bout, out);
}

// Round 21
// 89.777 us; speedup vs baseline: 4.2700x; 1.0272x over previous
//
#include <hip/hip_runtime.h>
#include <hip/hip_bf16.h>
#include <math.h>
#include <stdint.h>

// ---------------------------------------------------------------------------
// Attention (B=4, N=2048, D=512, H=8, Dh=64) for MI355X.
// Precision plan (threshold 6.48e-3; measured floor 1.95e-3):
//   x@Wqkv: 1-term bf16 (fused f32->bf16 A-cast).  QK^T: bf16.  PV: bf16.
//   out GEMM 1-term with fused exact log2-domain split-KV merge on A.
// R21: k_gemm_out retiled 128x128 -> 64x128 (grid 512 = 2 blocks/CU = 8
// waves/CU, was 1 block/CU): A-image 4KB merge-staged, B 8KB, 24KB dbuf,
// same counted-prefetch discipline.  k_attn + k_gemm_qkv + k_prep unchanged.
// ---------------------------------------------------------------------------

typedef unsigned short u16;
typedef __attribute__((ext_vector_type(4))) float f32x4;
typedef __attribute__((ext_vector_type(8))) short bf16x8;   // 8 bf16 = 4 VGPRs
typedef __attribute__((ext_vector_type(4))) short s16x4;

#define AS1 __attribute__((address_space(1)))
#define AS3 __attribute__((address_space(3)))
#define MFMA(a, b, c) __builtin_amdgcn_mfma_f32_16x16x32_bf16(a, b, c, 0, 0, 0)
#define QSCALE 0.180336880f   /* 0.125 * log2(e): logits in log2 domain */

__device__ __forceinline__ u16 f2bf(float f) {
  union { float f; unsigned u; } v; v.f = f;
  unsigned r = v.u + 0x7FFFu + ((v.u >> 16) & 1u);   // RNE
  return (u16)(r >> 16);
}
__device__ __forceinline__ float bf2f(u16 b) {
  union { unsigned u; float f; } v; v.u = ((unsigned)b) << 16; return v.f;
}
__device__ __forceinline__ void gld16(const u16* g, u16* l) {
  __builtin_amdgcn_global_load_lds((const AS1 void*)g, (AS3 void*)l, 16, 0, 0);
}
__device__ __forceinline__ float u2f(unsigned u) {
  union { unsigned u; float f; } v; v.u = u; return v.f;
}
__device__ __forceinline__ unsigned f2u(float f) {
  union { float f; unsigned u; } v; v.f = f; return v.u;
}
__device__ __forceinline__ int cvtpk(float lo, float hi) {
  int r; asm("v_cvt_pk_bf16_f32 %0, %1, %2" : "=v"(r) : "v"(lo), "v"(hi));
  return r;
}
__device__ __forceinline__ float fexp2(float x) {
  float r; asm("v_exp_f32 %0, %1" : "=v"(r) : "v"(x));
  return r;
}

// ---------------- prep: weight transposes only (64x64 LDS tiles) ------------
__global__ __launch_bounds__(256) void k_prep(
    const float* __restrict__ wqkv, u16* __restrict__ wqh,
    const float* __restrict__ wout, u16* __restrict__ woh) {
  const int bid = blockIdx.x, tid = threadIdx.x;
  __shared__ u16 lds[64][66];
  const float* src; u16* dst; int N, n0, k0;
  if (bid < 192) {
    src = wqkv; dst = wqh; N = 1536;
    n0 = (bid % 24) * 64; k0 = (bid / 24) * 64;
  } else {
    const int b3 = bid - 192;
    src = wout; dst = woh; N = 512;
    n0 = (b3 & 7) * 64; k0 = (b3 >> 3) * 64;
  }
  const int c = tid & 63, q = tid >> 6;
  #pragma unroll
  for (int s = 0; s < 16; ++s) {
    const int kr = q * 16 + s;
    lds[c][kr] = f2bf(src[(size_t)(k0 + kr) * N + n0 + c]);
  }
  __syncthreads();
  #pragma unroll
  for (int s = 0; s < 16; ++s) {
    const int nr = q * 16 + s;
    dst[(size_t)(n0 + nr) * 512 + k0 + c] = lds[nr][c];
  }
}

// ---------------- QKV projection: A = f32 x (fused cast), B = bf16 WqkvT ----
__global__ __launch_bounds__(256) void k_gemm_qkv(
    const float* __restrict__ xf, const u16* __restrict__ Bh,
    u16* __restrict__ Qb, u16* __restrict__ Kb, u16* __restrict__ Vt) {
  __shared__ __align__(1024) char sm[32768];
  const int tid = threadIdx.x, lane = tid & 63, wid = tid >> 6;
  const int x = lane & 15, h = lane >> 4;
  const int wr = wid >> 1, wc = wid & 1;
  const int rowA = blockIdx.x * 128, rowB = blockIdx.y * 128;

  const int d0 = tid * 16;
  const int lg0 = d0 ^ (((d0 >> 7) & 7) << 4);
  const int srow = lg0 >> 6;
  const int scol = (lg0 & 63) >> 1;
  const int swk = ((lane >> 1) & 7) << 4;
  const int rdoA = ((wr * 64 + x) * 64 + h * 16) ^ swk;
  const int rdoB = (((wc * 64 + x) * 64 + h * 16) ^ swk) + 8192;

  f32x4 acc[4][4] = {};

  {  // prologue: A(0) f32 loads -> B(0) gld16 -> cvt+write
    f32x4 a0[2], a1[2];
    #pragma unroll
    for (int r = 0; r < 2; ++r) {
      const float* src = xf + (size_t)(rowA + r * 64 + srow) * 512 + scol;
      a0[r] = *(const f32x4*)src;
      a1[r] = *(const f32x4*)(src + 4);
    }
    #pragma unroll
    for (int r = 0; r < 2; ++r) {
      const size_t gb = (size_t)(rowB + r * 64 + srow) * 512 + scol;
      gld16(Bh + gb, (u16*)(sm + 8192 + r * 4096 + d0));
    }
    #pragma unroll
    for (int r = 0; r < 2; ++r) {
      union { int w[4]; bf16x8 v; } uu;
      uu.w[0] = cvtpk(a0[r][0], a0[r][1]);
      uu.w[1] = cvtpk(a0[r][2], a0[r][3]);
      uu.w[2] = cvtpk(a1[r][0], a1[r][1]);
      uu.w[3] = cvtpk(a1[r][2], a1[r][3]);
      *(bf16x8*)(sm + r * 4096 + d0) = uu.v;
    }
    asm volatile("s_waitcnt lgkmcnt(0)" ::: "memory");
    __builtin_amdgcn_sched_barrier(0);
  }

  for (int kt = 0; kt < 16; ++kt) {
    const int bb = (kt & 1) * 16384;
    asm volatile("s_barrier" ::: "memory");       // alt buf free
    if (kt < 15) {
      char* buf = sm + (16384 - bb);
      const int kofs = (kt + 1) * 32;
      f32x4 a0[2], a1[2];
      #pragma unroll
      for (int r = 0; r < 2; ++r) {               // A f32 loads FIRST
        const float* src = xf + (size_t)(rowA + r * 64 + srow) * 512 +
                           kofs + scol;
        a0[r] = *(const f32x4*)src;
        a1[r] = *(const f32x4*)(src + 4);
      }
      #pragma unroll
      for (int r = 0; r < 2; ++r) {               // then B gld16 (newest)
        const size_t gb = (size_t)(rowB + r * 64 + srow) * 512 + kofs + scol;
        gld16(Bh + gb, (u16*)(buf + 8192 + r * 4096 + d0));
      }
      #pragma unroll
      for (int r = 0; r < 2; ++r) {               // cvt+write (waits vmcnt(2))
        union { int w[4]; bf16x8 v; } uu;
        uu.w[0] = cvtpk(a0[r][0], a0[r][1]);
        uu.w[1] = cvtpk(a0[r][2], a0[r][3]);
        uu.w[2] = cvtpk(a1[r][0], a1[r][1]);
        uu.w[3] = cvtpk(a1[r][2], a1[r][3]);
        *(bf16x8*)(buf + r * 4096 + d0) = uu.v;
      }
      asm volatile("s_waitcnt vmcnt(2)" ::: "memory");   // B(kt) landed
      asm volatile("s_waitcnt lgkmcnt(0)" ::: "memory"); // A writes retired
      __builtin_amdgcn_sched_barrier(0);
    } else {
      asm volatile("s_waitcnt vmcnt(0)" ::: "memory");
    }
    asm volatile("s_barrier" ::: "memory");       // tile kt published

    bf16x8 a_h[4], b_h[4];
    #pragma unroll
    for (int i = 0; i < 4; ++i)
      a_h[i] = *(const bf16x8*)(sm + bb + rdoA + i * 1024);
    #pragma unroll
    for (int j = 0; j < 4; ++j)
      b_h[j] = *(const bf16x8*)(sm + bb + rdoB + j * 1024);
    __builtin_amdgcn_s_setprio(1);
    #pragma unroll
    for (int i = 0; i < 4; ++i)
      #pragma unroll
      for (int j = 0; j < 4; ++j)
        acc[i][j] = MFMA(a_h[i], b_h[j], acc[i][j]);
    __builtin_amdgcn_s_setprio(0);
  }

  #pragma unroll
  for (int i = 0; i < 4; ++i)
    #pragma unroll
    for (int j = 0; j < 4; ++j) {
      const int n = rowB + wc * 64 + j * 16 + x;
      const int which = n >> 9;
      const int hh = (n >> 6) & 7, d = n & 63;
      const int m0 = rowA + wr * 64 + i * 16 + h * 4;
      const int b = m0 >> 11, is0 = m0 & 2047;
      if (which == 0) {
        #pragma unroll
        for (int r = 0; r < 4; ++r) {
          const size_t idx = ((size_t)((b * 8 + hh) * 2048 + is0 + r)) * 64 + d;
          Qb[idx] = f2bf(acc[i][j][r] * QSCALE);
        }
      } else if (which == 1) {
        #pragma unroll
        for (int r = 0; r < 4; ++r) {
          const size_t idx = ((size_t)((b * 8 + hh) * 2048 + is0 + r)) * 64 + d;
          Kb[idx] = f2bf(acc[i][j][r]);
        }
      } else {
        s16x4 vv;
        #pragma unroll
        for (int r = 0; r < 4; ++r) vv[r] = (short)f2bf(acc[i][j][r]);
        *(s16x4*)&Vt[((size_t)((b * 8 + hh) * 64 + d)) * 2048 + is0] = vv;
      }
    }
}

// ---------------- output projection, 64x128 tile, fused combine -------------
// Grid 512 (128 row-tiles x 4 col-tiles) = 2 blocks/CU (was 1).  A-image
// 4KB (merge-staged from OP halves), B 8KB, buf 12KB, dbuf 24KB.
// OP reg loads FIRST, then B gld16, merge+write waits vmcnt(2) via regs.
__global__ __launch_bounds__(256) void k_gemm_out(
    const u16* __restrict__ OP, const float* __restrict__ Mm,
    const float* __restrict__ Sm, const u16* __restrict__ Bh,
    const float* __restrict__ bias, float* __restrict__ out) {
  __shared__ __align__(1024) char sm[24576];
  const int tid = threadIdx.x, lane = tid & 63, wid = tid >> 6;
  const int x = lane & 15, h = lane >> 4;
  const int wr = wid >> 1, wc = wid & 1;
  const int fid = blockIdx.x;
  const int rowA = (fid >> 2) * 64, rowB = (fid & 3) * 128;

  const int d0 = tid * 16;                 // A dest [0,4K); B dest r*4K+d0+4K
  const int lg0 = d0 ^ (((d0 >> 7) & 7) << 4);
  const int srow = lg0 >> 6;               // 0..63
  const int scol = (lg0 & 63) >> 1;
  const int swk = ((lane >> 1) & 7) << 4;
  const int rdoA = ((wr * 32 + x) * 64 + h * 16) ^ swk;
  const int rdoB = (((wc * 64 + x) * 64 + h * 16) ^ swk) + 4096;

  const int m = rowA + srow;               // single staged A-row per thread
  const int bseq = (m >> 11) * 8;
  const int srw = m & 2047;

  // ---- precompute merge weights for this row x all 8 heads
  float w1p[8], w2p[8];
  #pragma unroll
  for (int hd = 0; hd < 8; ++hd) {
    const int rb = (bseq + hd) * 2048 + srw;
    const float m1 = Mm[rb], m2 = Mm[65536 + rb];
    const float s1 = Sm[rb], s2 = Sm[65536 + rb];
    const float mm = fmaxf(m1, m2);
    const float a1 = fexp2(m1 - mm), a2 = fexp2(m2 - mm);
    const float inv = 1.0f / (s1 * a1 + s2 * a2);
    w1p[hd] = a1 * inv; w2p[hd] = a2 * inv;
  }

  f32x4 acc[2][4] = {};

  auto loadA = [&](int kt, bf16x8& p1, bf16x8& p2) {
    const int head = kt >> 1;
    const int dd = (kt & 1) * 32 + scol;
    const int rb = (bseq + head) * 2048 + srw;
    p1 = *(const bf16x8*)&OP[(size_t)rb * 64 + dd];
    p2 = *(const bf16x8*)&OP[4194304 + (size_t)rb * 64 + dd];
  };
  auto writeA = [&](int kt, const bf16x8& p1, const bf16x8& p2, char* buf) {
    const int head = kt >> 1;
    const float w1 = w1p[head], w2 = w2p[head];
    union { int w[4]; bf16x8 v; } uu;
    #pragma unroll
    for (int q = 0; q < 4; ++q) {
      float lo = bf2f((u16)p1[2 * q]) * w1 + bf2f((u16)p2[2 * q]) * w2;
      float hi = bf2f((u16)p1[2 * q + 1]) * w1 + bf2f((u16)p2[2 * q + 1]) * w2;
      uu.w[q] = cvtpk(lo, hi);
    }
    *(bf16x8*)(buf + d0) = uu.v;
  };

  {  // prologue: A(0) loads -> B(0) gld16 -> merge+write into buf0
    bf16x8 p1, p2;
    loadA(0, p1, p2);
    #pragma unroll
    for (int r = 0; r < 2; ++r) {
      const size_t gb = (size_t)(rowB + r * 64 + srow) * 512 + scol;
      gld16(Bh + gb, (u16*)(sm + 4096 + r * 4096 + d0));
    }
    writeA(0, p1, p2, sm);
    asm volatile("s_waitcnt lgkmcnt(0)" ::: "memory");
    __builtin_amdgcn_sched_barrier(0);
  }

  #pragma unroll
  for (int kt = 0; kt < 16; ++kt) {
    const int bb = (kt & 1) * 12288;
    asm volatile("s_barrier" ::: "memory");       // alt buf free
    if (kt < 15) {
      char* buf = sm + (12288 - bb);
      const int kofs = (kt + 1) * 32;
      bf16x8 p1, p2;
      loadA(kt + 1, p1, p2);                      // OP reg loads FIRST
      #pragma unroll
      for (int r = 0; r < 2; ++r) {               // then B gld16 (newest)
        const size_t gb = (size_t)(rowB + r * 64 + srow) * 512 + kofs + scol;
        gld16(Bh + gb, (u16*)(buf + 4096 + r * 4096 + d0));
      }
      writeA(kt + 1, p1, p2, buf);                // waits vmcnt(2) via regs
      asm volatile("s_waitcnt vmcnt(2)" ::: "memory");   // B(kt) landed
      asm volatile("s_waitcnt lgkmcnt(0)" ::: "memory"); // A writes retired
      __builtin_amdgcn_sched_barrier(0);
    } else {
      asm volatile("s_waitcnt vmcnt(0)" ::: "memory");
    }
    asm volatile("s_barrier" ::: "memory");       // tile kt published

    bf16x8 a_h[2], b_h[4];
    #pragma unroll
    for (int i = 0; i < 2; ++i)
      a_h[i] = *(const bf16x8*)(sm + bb + rdoA + i * 1024);
    #pragma unroll
    for (int j = 0; j < 4; ++j)
      b_h[j] = *(const bf16x8*)(sm + bb + rdoB + j * 1024);
    __builtin_amdgcn_s_setprio(1);
    #pragma unroll
    for (int i = 0; i < 2; ++i)
      #pragma unroll
      for (int j = 0; j < 4; ++j)
        acc[i][j] = MFMA(a_h[i], b_h[j], acc[i][j]);
    __builtin_amdgcn_s_setprio(0);
  }

  #pragma unroll
  for (int i = 0; i < 2; ++i)
    #pragma unroll
    for (int j = 0; j < 4; ++j) {
      const int n = rowB + wc * 64 + j * 16 + x;
      #pragma unroll
      for (int r = 0; r < 4; ++r) {
        const int mm_ = rowA + wr * 32 + i * 16 + h * 4 + r;
        out[(size_t)mm_ * 512 + n] = acc[i][j][r] + bias[n];
      }
    }
}

// ---------------- flash attention, split-KV half, 8-wave blocks -------------
// (R14 body: ~51us, 16 waves/CU structural ceiling)
__global__ __launch_bounds__(512, 2) void k_attn(
    const u16* __restrict__ Qb,
    const u16* __restrict__ Kb, const u16* __restrict__ Vt,
    u16* __restrict__ OP,          // [2][32*2048*64] bf16 (+half*4194304)
    float* __restrict__ Mm,        // [2][65536]
    float* __restrict__ Sm) {      // [2][65536]
  __shared__ __align__(1024) char sm[65536];
  const int tid = threadIdx.x, wid = tid >> 6, lane = tid & 63;
  const int x = lane & 15, h = lane >> 4;

  const int fid = blockIdx.x;
  const int l = (fid & 7) * 64 + (fid >> 3);
  const int half = l & 1, qb = (l >> 1) & 7, bh = l >> 4;

  const size_t base = (size_t)bh * 2048 * 64;
  const int qr0 = qb * 256 + wid * 32;
  const size_t kv0 = (size_t)half * 1024;

  bf16x8 qh[2][2];
  #pragma unroll
  for (int g = 0; g < 2; ++g) {
    const size_t rq = base + (size_t)(qr0 + g * 16 + x) * 64 + h * 8;
    #pragma unroll
    for (int ks = 0; ks < 2; ++ks)
      qh[g][ks] = *(const bf16x8*)&Qb[rq + ks * 32];
  }

  bf16x8 ones;
  #pragma unroll
  for (int j = 0; j < 8; ++j) ones[j] = (short)0x3F80;

  const int db = tid * 16;
  const int lg = db ^ (((db >> 7) & 7) << 4);
  const int sks  = db >> 12;
  const int srow = (lg >> 6) & 63;
  const int scb  = (lg & 63) >> 1;
  const size_t offK = (size_t)srow * 64 + sks * 32 + scb;
  const size_t offV = (size_t)srow * 2048 + sks * 32 + scb;

  const int swk = ((lane >> 1) & 7) << 4;
  const int rdo = (x * 64 + h * 16) ^ swk;
  char* const pb = sm + 32768 + wid * 4096;
  const int pxor = (x & 7) << 4;
  const int prow = x * 128;

  float mrun[2] = {-INFINITY, -INFINITY};
  f32x4 o[2][4] = {};
  f32x4 os[2] = {};

  {
    gld16(Kb + base + kv0 * 64 + offK, (u16*)(sm + db));
    gld16(Vt + base + kv0 + offV,      (u16*)(sm + 8192 + db));
  }

  for (int kv = 0; kv < 16; ++kv) {
    const int bb = (kv & 1) * 16384;
    __builtin_amdgcn_s_barrier();
    if (kv < 15) {
      const size_t kvb = kv0 + (size_t)(kv + 1) * 64;
      char* buf = sm + (16384 - bb);
      gld16(Kb + base + kvb * 64 + offK, (u16*)(buf + db));
      gld16(Vt + base + kvb + offV,      (u16*)(buf + 8192 + db));
      asm volatile("s_waitcnt vmcnt(2)" ::: "memory");
    } else {
      asm volatile("s_waitcnt vmcnt(0)" ::: "memory");
    }
    __builtin_amdgcn_s_barrier();

    const char* smb = sm + bb + rdo;

    f32x4 s[2][4] = {};
    __builtin_amdgcn_s_setprio(1);
    #pragma unroll
    for (int c = 0; c < 4; ++c)
      #pragma unroll
      for (int ks = 0; ks < 2; ++ks) {
        bf16x8 kb_ = *(const bf16x8*)(smb + ks * 4096 + c * 1024);
        s[0][c] = MFMA(kb_, qh[0][ks], s[0][c]);
        s[1][c] = MFMA(kb_, qh[1][ks], s[1][c]);
      }
    __builtin_amdgcn_s_setprio(0);

    float pm[2];
    #pragma unroll
    for (int g = 0; g < 2; ++g) {
      float m0 = fmaxf(fmaxf(s[g][0][0], s[g][0][1]), s[g][0][2]);
      float m1 = fmaxf(fmaxf(s[g][0][3], s[g][1][0]), s[g][1][1]);
      float m2 = fmaxf(fmaxf(s[g][1][2], s[g][1][3]), s[g][2][0]);
      float m3 = fmaxf(fmaxf(s[g][2][1], s[g][2][2]), s[g][2][3]);
      float m4 = fmaxf(fmaxf(s[g][3][0], s[g][3][1]), s[g][3][2]);
      float m5 = fmaxf(fmaxf(m0, m1), m2);
      float p  = fmaxf(fmaxf(fmaxf(m3, m4), s[g][3][3]), m5);
      p = fmaxf(p, __shfl_xor(p, 16, 64));
      p = fmaxf(p, __shfl_xor(p, 32, 64));
      pm[g] = p;
    }

    if (__any((pm[0] > mrun[0] + 7.0f) || (pm[1] > mrun[1] + 7.0f))) {
      #pragma unroll
      for (int g = 0; g < 2; ++g) {
        float mnew = fmaxf(mrun[g], pm[g]);
        float scl = fexp2(mrun[g] - mnew);
        mrun[g] = mnew;
        #pragma unroll
        for (int r = 0; r < 4; ++r) {
          float sq = u2f((unsigned)__builtin_amdgcn_ds_bpermute(
              (20 * h + r) * 4, (int)f2u(scl)));
          os[g][r] *= sq;
          #pragma unroll
          for (int dg = 0; dg < 4; ++dg) o[g][dg][r] *= sq;
        }
      }
    }

    #pragma unroll
    for (int g = 0; g < 2; ++g)
      #pragma unroll
      for (int c = 0; c < 4; ++c) {
        int w0 = cvtpk(fexp2(s[g][c][0] - mrun[g]),
                       fexp2(s[g][c][1] - mrun[g]));
        int w1 = cvtpk(fexp2(s[g][c][2] - mrun[g]),
                       fexp2(s[g][c][3] - mrun[g]));
        int* dst = (int*)(pb + g * 2048 + prow + ((c * 32 + h * 8) ^ pxor));
        dst[0] = w0; dst[1] = w1;
      }

    __builtin_amdgcn_s_setprio(1);
    #pragma unroll
    for (int ch = 0; ch < 2; ++ch) {
      bf16x8 pa0 = *(const bf16x8*)(pb + prow +
                                    ((ch * 64 + h * 16) ^ pxor));
      bf16x8 pa1 = *(const bf16x8*)(pb + 2048 + prow +
                                    ((ch * 64 + h * 16) ^ pxor));
      os[0] = MFMA(pa0, ones, os[0]);
      os[1] = MFMA(pa1, ones, os[1]);
      #pragma unroll
      for (int dg = 0; dg < 4; ++dg) {
        bf16x8 vb = *(const bf16x8*)(smb + 8192 + ch * 4096 + dg * 1024);
        o[0][dg] = MFMA(pa0, vb, o[0][dg]);
        o[1][dg] = MFMA(pa1, vb, o[1][dg]);
      }
    }
    __builtin_amdgcn_s_setprio(0);
  }

  u16* op = OP + (size_t)half * 4194304 + ((size_t)(bh * 2048 + qr0)) * 64;
  #pragma unroll
  for (int g = 0; g < 2; ++g) {
    #pragma unroll
    for (int r = 0; r < 4; ++r) {
      const int row = g * 16 + h * 4 + r;
      #pragma unroll
      for (int dg = 0; dg < 4; ++dg)
        op[(size_t)row * 64 + dg * 16 + x] = f2bf(o[g][dg][r]);
      if (x == 0)
        Sm[half * 65536 + bh * 2048 + qr0 + g * 16 + h * 4 + r] = os[g][r];
    }
    if (h == 0)
      Mm[half * 65536 + bh * 2048 + qr0 + g * 16 + x] = mrun[g];
  }
}

// ---------------------------------------------------------------------------
extern "C" void kernel_launch(void* const* d_in, const int* in_sizes, int n_in,
                              void* d_out, int out_size, void* d_ws, size_t ws_size,
                              hipStream_t stream) {
  const float* x    = (const float*)d_in[0];
  const float* wqkv = (const float*)d_in[1];
  const float* wout = (const float*)d_in[2];
  const float* bout = (const float*)d_in[3];
  float* out = (float*)d_out;

  char* w = (char*)d_ws;
  u16* wqh = (u16*)(w + 16777216);    // WqkvT [1536][512] (dead after qkv)
  u16* woh = (u16*)(w + 19922944);    // WoutT [512][512] (live to end)
  u16* Qb  = (u16*)(w + 20971520);    // [32][2048][64] bf16 (pre-scaled)
  u16* Kb  = (u16*)(w + 37748736);    // [32][2048][64] bf16
  u16* Vt  = (u16*)(w + 46137344);    // [32][64][2048] bf16
  // Split-KV partials (alias dead regions):
  u16*   OP = (u16*)(w + 0);          // [2][4194304] bf16 = 16MB
  float* Mm = (float*)(w + 16777216); // [2][65536] f32 (after attn; wqh dead)
  float* Sm = (float*)(w + 17301504); // [2][65536] f32 (ends < woh)

  k_prep<<<256, 256, 0, stream>>>(wqkv, wqh, wout, woh);
  k_gemm_qkv<<<dim3(64, 12), 256, 0, stream>>>(x, wqh, Qb, Kb, Vt);
  k_attn<<<512, 512, 0, stream>>>(Qb, Kb, Vt, OP, Mm, Sm);
  k_gemm_out<<<512, 256, 0, stream>>>(OP, Mm, Sm, woh, bout, out);
}